// Round 1
// baseline (704.341 us; speedup 1.0000x reference)
//
#include <hip/hip_runtime.h>

// MoE top-2 dispatcher, B=4 S=1024 D=1024 E=8 F=4096.
// Plan: gate -> pack pairs per expert -> grouped GEMM (bf16 MFMA 16x16x32,
// m97-style 128x128 tile, BK=32, global_load_lds width 16) -> gelu -> GEMM ->
// weighted atomicAdd scatter to out.
//
// ws layout (bytes):
//   0         : int counts[8]                (memset to 0 each call)
//   64        : int offsets[9]
//   4096      : int tok_list[8][2048]        (64 KB)
//   +64K      : float w_list[8][2048]        (64 KB)
//   +128K     : int tok_pack[8192]           (32 KB)
//   +160K     : float w_pack[8192]           (32 KB)
//   256K      : ushort Xg[8192][1024]        (16 MiB)  packed bf16 tokens
//   +16M      : ushort H[8192][4096]         (64 MiB)  gelu(X W1 + b1) bf16
//   +80M      : ushort W1t[8][4096][1024]    (64 MiB)  bf16, [e][f][d]
//   +144M     : ushort W2t[8][1024][4096]    (64 MiB)  bf16, [e][d][f]
//   total ~208.25 MiB

#define E_ 8
#define D_ 1024
#define F_ 4096
#define NTOK 4096
#define NPAIR 8192
#define CAP 2048

typedef short bf16x8 __attribute__((ext_vector_type(8)));
typedef float f32x4 __attribute__((ext_vector_type(4)));

#define GLOBAL_AS __attribute__((address_space(1)))
#define LDS_AS __attribute__((address_space(3)))

__device__ __forceinline__ ushort f2bf(float f) {
  unsigned u = __builtin_bit_cast(unsigned, f);
  unsigned r = (u + 0x7FFFu + ((u >> 16) & 1u)) >> 16;
  return (ushort)r;
}

// ---------------- gating: top-2 of 8, renormalize, scatter ----------------
__global__ void gate_kernel(const float* __restrict__ rw, int* __restrict__ counts,
                            int* __restrict__ tok_list, float* __restrict__ w_list) {
  int t = blockIdx.x * 256 + threadIdx.x;
  if (t >= NTOK) return;
  float v[E_];
#pragma unroll
  for (int e = 0; e < E_; ++e) v[e] = rw[t * E_ + e];
  int i0 = 0;
  float m0 = v[0];
#pragma unroll
  for (int e = 1; e < E_; ++e)
    if (v[e] > m0) { m0 = v[e]; i0 = e; }
  int i1 = -1;
  float m1 = -1e30f;
#pragma unroll
  for (int e = 0; e < E_; ++e)
    if (e != i0 && v[e] > m1) { m1 = v[e]; i1 = e; }
  float denom = fmaxf(m0 + m1, 1e-9f);
  float w0 = m0 / denom, w1 = m1 / denom;
  int p0 = atomicAdd(&counts[i0], 1);
  if (p0 < CAP) { tok_list[i0 * CAP + p0] = t; w_list[i0 * CAP + p0] = w0; }
  int p1 = atomicAdd(&counts[i1], 1);
  if (p1 < CAP) { tok_list[i1 * CAP + p1] = t; w_list[i1 * CAP + p1] = w1; }
}

// ---------------- exclusive prefix over 8 counts ----------------
__global__ void scan_kernel(const int* __restrict__ counts, int* __restrict__ offsets) {
  if (threadIdx.x == 0) {
    int a = 0;
    for (int e = 0; e < E_; ++e) {
      offsets[e] = a;
      int c = counts[e];
      if (c > CAP) c = CAP;
      a += c;
    }
    offsets[E_] = a;
  }
}

// ---------------- gather tokens into packed bf16 rows ----------------
__global__ __launch_bounds__(256) void gather_kernel(
    const float* __restrict__ hidden, const int* __restrict__ counts,
    const int* __restrict__ offsets, const int* __restrict__ tok_list,
    const float* __restrict__ w_list, ushort* __restrict__ Xg,
    int* __restrict__ tok_pack, float* __restrict__ w_pack) {
  int bid = blockIdx.x;
  int e = bid >> 11;        // /CAP
  int pos = bid & (CAP - 1);
  int cnt = counts[e];
  if (cnt > CAP) cnt = CAP;
  if (pos >= cnt) return;
  int row = offsets[e] + pos;
  int t = tok_list[e * CAP + pos];
  if (threadIdx.x == 0) {
    tok_pack[row] = t;
    w_pack[row] = w_list[e * CAP + pos];
  }
  float4 v = *(const float4*)(hidden + (size_t)t * D_ + threadIdx.x * 4);
  ushort4 o;
  o.x = f2bf(v.x); o.y = f2bf(v.y); o.z = f2bf(v.z); o.w = f2bf(v.w);
  *(ushort4*)(Xg + (size_t)row * D_ + threadIdx.x * 4) = o;
}

// ---------------- transpose + fp32->bf16: dst[e][c][r] = src[e][r][c] ----------------
__global__ __launch_bounds__(256) void transpose_bf16(const float* __restrict__ src,
                                                      ushort* __restrict__ dst, int R, int C) {
  __shared__ ushort t[64][65];
  int e = blockIdx.z;
  int r0 = blockIdx.y * 64, c0 = blockIdx.x * 64;
  const float* s = src + (size_t)e * R * C;
  int tr = threadIdx.x >> 4;          // 0..15
  int tc = (threadIdx.x & 15) * 4;    // 0..60
#pragma unroll
  for (int i = 0; i < 4; ++i) {
    int r = tr + i * 16;
    float4 v = *(const float4*)(s + (size_t)(r0 + r) * C + c0 + tc);
    t[r][tc + 0] = f2bf(v.x);
    t[r][tc + 1] = f2bf(v.y);
    t[r][tc + 2] = f2bf(v.z);
    t[r][tc + 3] = f2bf(v.w);
  }
  __syncthreads();
  ushort* d = dst + (size_t)e * C * R;
#pragma unroll
  for (int i = 0; i < 4; ++i) {
    int oc = tr + i * 16;  // index along C (output row)
    ushort4 o;
    o.x = t[tc + 0][oc];
    o.y = t[tc + 1][oc];
    o.z = t[tc + 2][oc];
    o.w = t[tc + 3][oc];
    *(ushort4*)(d + (size_t)(c0 + oc) * R + r0 + tc) = o;
  }
}

// ---------------- grouped GEMM, 128x128 tile, BK=32, bf16 MFMA ----------------
// A: [NPAIR][K] bf16 row-major (k contiguous). B: [E][N][K] bf16 (B^T layout).
// PASS 0: out = gelu(acc + b1) -> H bf16.  PASS 1: atomicAdd(out[tok], w*(acc+b2)).
template <int PASS>
__global__ __launch_bounds__(256) void gemm_kernel(
    const ushort* __restrict__ A, const ushort* __restrict__ B,
    const int* __restrict__ offsets, const int* __restrict__ tok_pack,
    const float* __restrict__ w_pack, const float* __restrict__ bias,
    void* __restrict__ outp, int K, int N) {
  __shared__ ushort As[128 * 32];
  __shared__ ushort Bs[128 * 32];
  const int e = blockIdx.z;
  const int rb = blockIdx.y;
  const int cb = blockIdx.x;
  const int seg_lo = offsets[e], seg_hi = offsets[e + 1];
  if (rb * 128 >= seg_hi - seg_lo) return;
  const int row0 = seg_lo + rb * 128;
  const int tid = threadIdx.x;
  const int l = tid & 63, w = tid >> 6;
  const int wr = w >> 1, wc = w & 1;

  f32x4 acc[4][4] = {};

  const ushort* Be = B + (size_t)e * N * K;
  const int colbase = cb * 128;
  const int arow_l = (l >> 2);      // row within 16-row chunk
  const int acol_l = (l & 3) * 8;   // k element offset within BK

  for (int kt = 0; kt < K; kt += 32) {
#pragma unroll
    for (int i = 0; i < 2; ++i) {
      int c = w + i * 4;  // chunk 0..7 (16 rows each)
      int r = c * 16 + arow_l;
      int grA = row0 + r;
      if (grA > NPAIR - 1) grA = NPAIR - 1;  // clamp: guarded at store
      const ushort* gpA = A + (size_t)grA * K + kt + acol_l;
      __builtin_amdgcn_global_load_lds((const GLOBAL_AS void*)gpA,
                                       (LDS_AS void*)(As + c * 512), 16, 0, 0);
      int grB = colbase + r;
      const ushort* gpB = Be + (size_t)grB * K + kt + acol_l;
      __builtin_amdgcn_global_load_lds((const GLOBAL_AS void*)gpB,
                                       (LDS_AS void*)(Bs + c * 512), 16, 0, 0);
    }
    __syncthreads();
    bf16x8 af[4], bf[4];
#pragma unroll
    for (int m = 0; m < 4; ++m)
      af[m] = *(const bf16x8*)(As + (wr * 64 + m * 16 + (l & 15)) * 32 + (l >> 4) * 8);
#pragma unroll
    for (int n = 0; n < 4; ++n)
      bf[n] = *(const bf16x8*)(Bs + (wc * 64 + n * 16 + (l & 15)) * 32 + (l >> 4) * 8);
#pragma unroll
    for (int m = 0; m < 4; ++m)
#pragma unroll
      for (int n = 0; n < 4; ++n)
        acc[m][n] = __builtin_amdgcn_mfma_f32_16x16x32_bf16(af[m], bf[n], acc[m][n], 0, 0, 0);
    __syncthreads();
  }

#pragma unroll
  for (int m = 0; m < 4; ++m) {
#pragma unroll
    for (int n = 0; n < 4; ++n) {
      int col = colbase + wc * 64 + n * 16 + (l & 15);
      float bv = bias[e * N + col];
#pragma unroll
      for (int reg = 0; reg < 4; ++reg) {
        int row = row0 + wr * 64 + m * 16 + (l >> 4) * 4 + reg;
        if (row < seg_hi) {
          if constexpr (PASS == 0) {
            float x = acc[m][n][reg] + bv;
            float x3 = x * x * x;
            float th = tanhf(0.7978845608028654f * (x + 0.044715f * x3));
            float g = 0.5f * x * (1.0f + th);
            ((ushort*)outp)[(size_t)row * N + col] = f2bf(g);
          } else {
            float val = w_pack[row] * (acc[m][n][reg] + bv);
            atomicAdd(&((float*)outp)[(size_t)tok_pack[row] * D_ + col], val);
          }
        }
      }
    }
  }
}

extern "C" void kernel_launch(void* const* d_in, const int* in_sizes, int n_in,
                              void* d_out, int out_size, void* d_ws, size_t ws_size,
                              hipStream_t stream) {
  const float* hidden = (const float*)d_in[0];
  const float* route = (const float*)d_in[1];
  const float* w1 = (const float*)d_in[2];
  const float* b1 = (const float*)d_in[3];
  const float* w2 = (const float*)d_in[4];
  const float* b2 = (const float*)d_in[5];
  float* out = (float*)d_out;

  char* ws = (char*)d_ws;
  int* counts = (int*)ws;
  int* offsets = (int*)(ws + 64);
  int* tok_list = (int*)(ws + 4096);
  float* w_list = (float*)(ws + 4096 + 65536);
  int* tok_pack = (int*)(ws + 4096 + 2 * 65536);
  float* w_pack = (float*)(ws + 4096 + 2 * 65536 + 32768);
  ushort* Xg = (ushort*)(ws + 262144);
  ushort* H = (ushort*)(ws + 262144 + (size_t)16 * 1024 * 1024);
  ushort* W1t = (ushort*)(ws + 262144 + (size_t)80 * 1024 * 1024);
  ushort* W2t = (ushort*)(ws + 262144 + (size_t)144 * 1024 * 1024);

  hipMemsetAsync(counts, 0, 64, stream);
  hipMemsetAsync(d_out, 0, (size_t)out_size * sizeof(float), stream);

  // weight convert+transpose: W1t[e][f][d], W2t[e][d][f]
  transpose_bf16<<<dim3(F_ / 64, D_ / 64, E_), 256, 0, stream>>>(w1, W1t, D_, F_);
  transpose_bf16<<<dim3(D_ / 64, F_ / 64, E_), 256, 0, stream>>>(w2, W2t, F_, D_);

  gate_kernel<<<NTOK / 256, 256, 0, stream>>>(route, counts, tok_list, w_list);
  scan_kernel<<<1, 64, 0, stream>>>(counts, offsets);
  gather_kernel<<<E_ * CAP, 256, 0, stream>>>(hidden, counts, offsets, tok_list,
                                              w_list, Xg, tok_pack, w_pack);

  // H = gelu(Xg @ W1 + b1)   [8192 x 4096], K=1024
  gemm_kernel<0><<<dim3(F_ / 128, CAP / 128, E_), 256, 0, stream>>>(
      Xg, W1t, offsets, tok_pack, w_pack, b1, H, D_, F_);
  // out[tok] += w * (H @ W2 + b2)   K=4096, N=1024
  gemm_kernel<1><<<dim3(D_ / 128, CAP / 128, E_), 256, 0, stream>>>(
      H, W2t, offsets, tok_pack, w_pack, b2, out, F_, D_);
}